// Round 3
// baseline (253.325 us; speedup 1.0000x reference)
//
#include <hip/hip_runtime.h>
#include <math.h>

// Problem constants
#define N_LEN 16384
#define NMODES 64
#define NROWS 1024          // B*C = 32*32
#define TWO_PI_OVER_N 3.8349519697141029e-04f

// ws layout (in floats)
#define T_OFF   0                         // T[n][k], 16384*64
#define TT_OFF  (N_LEN * NMODES)          // Tt[k][n], 64*16384
#define XM_OFF  (2 * N_LEN * NMODES)      // xm[row][k], 1024*64
#define Z_OFF   (XM_OFF + NROWS * NMODES) // z[row][k], 1024*64

// ---------------------------------------------------------------------------
// Build cas tables: T[n][k] = cas(2*pi*n*k/N), Tt[k][n] = transposed layout.
// ---------------------------------------------------------------------------
__global__ __launch_bounds__(256) void build_tables(float* __restrict__ ws) {
    int idx = blockIdx.x * 256 + threadIdx.x;   // 0 .. 2*1048576-1
    float* T  = ws + T_OFF;
    float* Tt = ws + TT_OFF;
    if (idx < N_LEN * NMODES) {
        int n = idx >> 6, k = idx & 63;
        int r = (n * k) & (N_LEN - 1);
        float th = (float)r * TWO_PI_OVER_N;
        float s, c;
        sincosf(th, &s, &c);
        T[idx] = c + s;
    } else {
        int j = idx - N_LEN * NMODES;
        int k = j >> 14, n = j & (N_LEN - 1);
        int r = (n * k) & (N_LEN - 1);
        float th = (float)r * TWO_PI_OVER_N;
        float s, c;
        sincosf(th, &s, &c);
        Tt[j] = c + s;
    }
}

// ---------------------------------------------------------------------------
// GEMM1: xm[row][k] = sum_n x[row][n] * T[n][k]
// Block: 128 rows x 64 k, 256 threads. Thread tile: 8 rows x 4 k
//   (kg = tid&15 -> k0 = 4*kg; rq = tid>>4 -> rows rq*8..+8).
// KSPLIT=64: grid (8, 64); chunk 256 n = 4 tiles of 64 n.
// Both x tile (128x64 = 32 KB) and T tile (64x64 = 16 KB) staged in LDS.
// Inner 4-n group: 8 x ds_read_b128 + 4 T ds_read_b128 per 128 FMA -> VALU-
// bound. Partials combined via fp32 atomicAdd (xm zeroed beforehand).
// ---------------------------------------------------------------------------
#define G1_ROWB 128
#define G1_KSPLIT 64
#define G1_CHUNK (N_LEN / G1_KSPLIT)   // 256
#define G1_TILE 64

__global__ __launch_bounds__(256) void gemm1(const float* __restrict__ x,
                                             const float* __restrict__ T,
                                             float* __restrict__ xm) {
    __shared__ float xt[G1_ROWB * G1_TILE];   // 32 KB
    __shared__ float tls[G1_TILE * NMODES];   // 16 KB
    const int tid = threadIdx.x;
    const int kg  = tid & 15;            // 16 k-groups of 4
    const int rq  = tid >> 4;            // 16 row-groups of 8
    const int k0  = kg * 4;
    const int row0 = blockIdx.x * G1_ROWB;
    const int n0   = blockIdx.y * G1_CHUNK;

    float4 acc[8];
#pragma unroll
    for (int r = 0; r < 8; ++r) acc[r] = make_float4(0.f, 0.f, 0.f, 0.f);

    for (int c = 0; c < G1_CHUNK / G1_TILE; ++c) {   // 4 tiles
        const int nc = n0 + c * G1_TILE;
        // stage x tile: 128 rows x 64 n -> 2048 float4, 8 per thread
#pragma unroll
        for (int j = 0; j < 8; ++j) {
            int f   = (j * 256 + tid) * 4;
            int row = f >> 6, nn = f & 63;
            *(float4*)(xt + f) =
                *(const float4*)(x + (size_t)(row0 + row) * N_LEN + nc + nn);
        }
        // stage T tile: 64 n x 64 k -> 1024 float4, 4 per thread
#pragma unroll
        for (int j = 0; j < 4; ++j) {
            int f = (j * 256 + tid) * 4;
            *(float4*)(tls + f) = *(const float4*)(T + (size_t)nc * NMODES + f);
        }
        __syncthreads();

#pragma unroll 4
        for (int g = 0; g < 16; ++g) {       // 4 n per group
            float4 tf0 = *(const float4*)(tls + (g * 4 + 0) * NMODES + k0);
            float4 tf1 = *(const float4*)(tls + (g * 4 + 1) * NMODES + k0);
            float4 tf2 = *(const float4*)(tls + (g * 4 + 2) * NMODES + k0);
            float4 tf3 = *(const float4*)(tls + (g * 4 + 3) * NMODES + k0);
#pragma unroll
            for (int r = 0; r < 8; ++r) {
                float4 xv = *(const float4*)(xt + (rq * 8 + r) * G1_TILE + g * 4);
                acc[r].x = fmaf(xv.x, tf0.x, acc[r].x);
                acc[r].y = fmaf(xv.x, tf0.y, acc[r].y);
                acc[r].z = fmaf(xv.x, tf0.z, acc[r].z);
                acc[r].w = fmaf(xv.x, tf0.w, acc[r].w);
                acc[r].x = fmaf(xv.y, tf1.x, acc[r].x);
                acc[r].y = fmaf(xv.y, tf1.y, acc[r].y);
                acc[r].z = fmaf(xv.y, tf1.z, acc[r].z);
                acc[r].w = fmaf(xv.y, tf1.w, acc[r].w);
                acc[r].x = fmaf(xv.z, tf2.x, acc[r].x);
                acc[r].y = fmaf(xv.z, tf2.y, acc[r].y);
                acc[r].z = fmaf(xv.z, tf2.z, acc[r].z);
                acc[r].w = fmaf(xv.z, tf2.w, acc[r].w);
                acc[r].x = fmaf(xv.w, tf3.x, acc[r].x);
                acc[r].y = fmaf(xv.w, tf3.y, acc[r].y);
                acc[r].z = fmaf(xv.w, tf3.z, acc[r].z);
                acc[r].w = fmaf(xv.w, tf3.w, acc[r].w);
            }
        }
        __syncthreads();
    }

#pragma unroll
    for (int r = 0; r < 8; ++r) {
        float* p = xm + (size_t)(row0 + rq * 8 + r) * NMODES + k0;
        atomicAdd(p + 0, acc[r].x);
        atomicAdd(p + 1, acc[r].y);
        atomicAdd(p + 2, acc[r].z);
        atomicAdd(p + 3, acc[r].w);
    }
}

// ---------------------------------------------------------------------------
// Mix: z[b][o][k] = (1/N) * sin(pw[0][o][k]) *
//      sum_i xm[b][i][k]*ye + xm[b][i][kf]*yo,  kf=(64-k)&63
// Grid: (b=32, og=8), block 256 = 4 o's x 64 k-lanes. 1/N folded here.
// ---------------------------------------------------------------------------
__global__ __launch_bounds__(256) void mixk(const float* __restrict__ xm,
                                            const float* __restrict__ w1,
                                            const float* __restrict__ pw,
                                            float* __restrict__ z) {
    int k = threadIdx.x & 63;
    int wave = threadIdx.x >> 6;
    int b = blockIdx.x;
    int o = blockIdx.y * 4 + wave;
    int kf = (NMODES - k) & 63;

    float acc = 0.f;
#pragma unroll 4
    for (int i = 0; i < 32; ++i) {
        float xv  = xm[(size_t)(b * 32 + i) * NMODES + k];
        float xvf = xm[(size_t)(b * 32 + i) * NMODES + kf];
        float w   = w1[(size_t)(i * 32 + o) * NMODES + k];
        float wf  = w1[(size_t)(i * 32 + o) * NMODES + kf];
        acc = fmaf(xv, 0.5f * (w + wf), acc);
        acc = fmaf(xvf, 0.5f * (w - wf), acc);
    }
    const float sc = 1.0f / (float)N_LEN;
    z[(size_t)(b * 32 + o) * NMODES + k] = acc * sinf(pw[(size_t)o * NMODES + k]) * sc;
}

// ---------------------------------------------------------------------------
// GEMM2: out[row][n] = sum_k z[row][k] * Tt[k][n]   (1/N already in z)
// Block: 32 rows x 512 n, 256 threads. Waves partition rows (8 each).
// Thread tile: 8 rows x 8 n (two float4 at nb and nb+256).
// Inner 4-k group: 8 broadcast zs ds_read_b128 + 8 coalesced Tt float4 loads
// per 256 FMA. Grid (32, 32) = 1024 blocks.
// ---------------------------------------------------------------------------
__global__ __launch_bounds__(256) void gemm2(const float* __restrict__ Tt,
                                             const float* __restrict__ z,
                                             float* __restrict__ out) {
    __shared__ float zs[32 * NMODES];       // 8 KB
    const int tid  = threadIdx.x;
    const int lane = tid & 63;
    const int w    = tid >> 6;              // wave -> rows w*8..+8
    const int row0 = blockIdx.x * 32;
    const int nb   = blockIdx.y * 512 + lane * 4;

    // stage z[32][64] coalesced: 512 float4, 2 per thread
#pragma unroll
    for (int j = 0; j < 2; ++j) {
        int f = (j * 256 + tid) * 4;
        *(float4*)(zs + f) = *(const float4*)(z + (size_t)row0 * NMODES + f);
    }
    __syncthreads();

    float4 acc0[8], acc1[8];
#pragma unroll
    for (int r = 0; r < 8; ++r) {
        acc0[r] = make_float4(0.f, 0.f, 0.f, 0.f);
        acc1[r] = make_float4(0.f, 0.f, 0.f, 0.f);
    }

#pragma unroll 4
    for (int g = 0; g < 16; ++g) {          // 4 k per group
        float4 zv[8];
#pragma unroll
        for (int r = 0; r < 8; ++r)
            zv[r] = *(const float4*)(zs + (w * 8 + r) * NMODES + g * 4);
#pragma unroll
        for (int jk = 0; jk < 4; ++jk) {
            int k = g * 4 + jk;
            float4 tv0 = *(const float4*)(Tt + (size_t)k * N_LEN + nb);
            float4 tv1 = *(const float4*)(Tt + (size_t)k * N_LEN + nb + 256);
#pragma unroll
            for (int r = 0; r < 8; ++r) {
                const float* zp = (const float*)&zv[r];
                float zc = zp[jk];
                acc0[r].x = fmaf(zc, tv0.x, acc0[r].x);
                acc0[r].y = fmaf(zc, tv0.y, acc0[r].y);
                acc0[r].z = fmaf(zc, tv0.z, acc0[r].z);
                acc0[r].w = fmaf(zc, tv0.w, acc0[r].w);
                acc1[r].x = fmaf(zc, tv1.x, acc1[r].x);
                acc1[r].y = fmaf(zc, tv1.y, acc1[r].y);
                acc1[r].z = fmaf(zc, tv1.z, acc1[r].z);
                acc1[r].w = fmaf(zc, tv1.w, acc1[r].w);
            }
        }
    }

#pragma unroll
    for (int r = 0; r < 8; ++r) {
        float* p = out + (size_t)(row0 + w * 8 + r) * N_LEN + nb;
        *(float4*)(p)       = acc0[r];
        *(float4*)(p + 256) = acc1[r];
    }
}

// ---------------------------------------------------------------------------
extern "C" void kernel_launch(void* const* d_in, const int* in_sizes, int n_in,
                              void* d_out, int out_size, void* d_ws, size_t ws_size,
                              hipStream_t stream) {
    const float* x  = (const float*)d_in[0];   // (32, 32, 16384)
    const float* w1 = (const float*)d_in[1];   // (32, 32, 64)
    const float* pw = (const float*)d_in[2];   // (32, 32, 64)
    float* out = (float*)d_out;                // (32, 32, 16384)
    float* ws  = (float*)d_ws;

    // Zero the xm accumulator (ws is re-poisoned before every call).
    hipMemsetAsync(ws + XM_OFF, 0, (size_t)NROWS * NMODES * sizeof(float), stream);

    build_tables<<<dim3((2 * N_LEN * NMODES) / 256), dim3(256), 0, stream>>>(ws);

    gemm1<<<dim3(NROWS / G1_ROWB, G1_KSPLIT), dim3(256), 0, stream>>>(x, ws + T_OFF, ws + XM_OFF);

    mixk<<<dim3(32, 8), dim3(256), 0, stream>>>(ws + XM_OFF, w1, pw, ws + Z_OFF);

    gemm2<<<dim3(32, 32), dim3(256), 0, stream>>>(ws + TT_OFF, ws + Z_OFF, out);
}

// Round 4
// 225.252 us; speedup vs baseline: 1.1246x; 1.1246x over previous
//
#include <hip/hip_runtime.h>
#include <math.h>

// Problem constants
#define N_LEN 16384
#define NMODES 64
#define NROWS 1024          // B*C = 32*32
#define TWO_PI_OVER_N 3.8349519697141029e-04f

// ---------------------------------------------------------------------------
// Build cas table Tt[k][n] = cas(2*pi*n*k/N)  (n contiguous; used by BOTH
// gemms: gemm1 reads per-k rows via L1, gemm2 reads coalesced along n).
// ---------------------------------------------------------------------------
__global__ __launch_bounds__(256) void build_tt(float* __restrict__ Tt) {
    int idx = blockIdx.x * 256 + threadIdx.x;   // 0 .. 1048576
    int k = idx >> 14, n = idx & (N_LEN - 1);
    int r = (n * k) & (N_LEN - 1);
    float s, c;
    sincosf((float)r * TWO_PI_OVER_N, &s, &c);
    Tt[idx] = c + s;
}

// ---------------------------------------------------------------------------
// GEMM1: part[s][row][k] = sum_{n in chunk s} x[row][n] * Tt[k][n]
// Block: 256 rows x 64 k, 256 threads, thread tile 8r x 8k
//   (kg = tid&7 -> k = kg*8+kk ; rg = tid>>3 -> rows rg*8..+8).
// x tile 256x32 (32 KB) in LDS, XOR-swizzled so the 8 row-groups of a wave
// hit distinct bank quads (8-lane broadcast each). Tt read from global
// (8 KB/k-tile working set -> L1). Per 4-n group: 8 LDS b128 + 8 L1 float4
// per 256 FMA insts -> VALU-bound. No atomics: per-split partials.
// ---------------------------------------------------------------------------
#define G1_BR 256
#define G1_TN 32

__global__ __launch_bounds__(256) void gemm1(const float* __restrict__ x,
                                             const float* __restrict__ Tt,
                                             float* __restrict__ part,
                                             int ntiles) {
    __shared__ float xt[G1_BR * G1_TN];     // 32 KB
    const int tid  = threadIdx.x;
    const int kg   = tid & 7;               // k-group (8 k's)
    const int rg   = tid >> 3;              // row-group (8 rows)
    const int row0 = blockIdx.x * G1_BR;
    const int chunk = ntiles * G1_TN;
    const int n0   = blockIdx.y * chunk;

    float acc[8][8];
#pragma unroll
    for (int r = 0; r < 8; ++r)
#pragma unroll
        for (int kk = 0; kk < 8; ++kk) acc[r][kk] = 0.f;

    const int swz = (rg & 7) << 2;

    for (int t = 0; t < ntiles; ++t) {
        const int nc = n0 + t * G1_TN;
        // stage x tile: 256 rows x 32 n = 2048 float4, 8 per thread
#pragma unroll
        for (int it = 0; it < 8; ++it) {
            int idx = it * 256 + tid;
            int row = idx >> 3;
            int nn  = (idx & 7) * 4;
            float4 v = *(const float4*)(x + (size_t)(row0 + row) * N_LEN + nc + nn);
            *(float4*)(xt + row * G1_TN + (nn ^ (((row >> 3) & 7) << 2))) = v;
        }
        __syncthreads();

#pragma unroll
        for (int g = 0; g < 8; ++g) {       // 4 n per group
            float4 xv[8];
#pragma unroll
            for (int r = 0; r < 8; ++r)
                xv[r] = *(const float4*)(xt + (rg * 8 + r) * G1_TN + ((g * 4) ^ swz));
            float4 tv[8];
#pragma unroll
            for (int kk = 0; kk < 8; ++kk)
                tv[kk] = *(const float4*)(Tt + (size_t)(kg * 8 + kk) * N_LEN + nc + g * 4);
#pragma unroll
            for (int kk = 0; kk < 8; ++kk) {
#pragma unroll
                for (int r = 0; r < 8; ++r) {
                    acc[r][kk] = fmaf(xv[r].x, tv[kk].x, acc[r][kk]);
                    acc[r][kk] = fmaf(xv[r].y, tv[kk].y, acc[r][kk]);
                    acc[r][kk] = fmaf(xv[r].z, tv[kk].z, acc[r][kk]);
                    acc[r][kk] = fmaf(xv[r].w, tv[kk].w, acc[r][kk]);
                }
            }
        }
        __syncthreads();
    }

    // store partials: two float4 per row
    float* pb = part + (size_t)blockIdx.y * (NROWS * NMODES)
                     + (size_t)(row0 + rg * 8) * NMODES + kg * 8;
#pragma unroll
    for (int r = 0; r < 8; ++r) {
        float4 a0 = make_float4(acc[r][0], acc[r][1], acc[r][2], acc[r][3]);
        float4 a1 = make_float4(acc[r][4], acc[r][5], acc[r][6], acc[r][7]);
        *(float4*)(pb + (size_t)r * NMODES)     = a0;
        *(float4*)(pb + (size_t)r * NMODES + 4) = a1;
    }
}

// ---------------------------------------------------------------------------
// Reduce: xm[row][k] = sum_s part[s][row][k]
// ---------------------------------------------------------------------------
__global__ __launch_bounds__(256) void reduce_xm(const float* __restrict__ part,
                                                 float* __restrict__ xm, int S) {
    int gid = blockIdx.x * 256 + threadIdx.x;   // 16384 threads, float4 each
    float4 a = make_float4(0.f, 0.f, 0.f, 0.f);
#pragma unroll 4
    for (int s = 0; s < S; ++s) {
        float4 v = *(const float4*)(part + (size_t)s * (NROWS * NMODES) + (size_t)gid * 4);
        a.x += v.x; a.y += v.y; a.z += v.z; a.w += v.w;
    }
    *(float4*)(xm + (size_t)gid * 4) = a;
}

// ---------------------------------------------------------------------------
// Mix: z[b][o][k] = (1/N) * sin(pw[0][o][k]) *
//      sum_i xm[b][i][k]*ye + xm[b][i][kf]*yo,  kf=(64-k)&63
// ---------------------------------------------------------------------------
__global__ __launch_bounds__(256) void mixk(const float* __restrict__ xm,
                                            const float* __restrict__ w1,
                                            const float* __restrict__ pw,
                                            float* __restrict__ z) {
    int k = threadIdx.x & 63;
    int wave = threadIdx.x >> 6;
    int b = blockIdx.x;
    int o = blockIdx.y * 4 + wave;
    int kf = (NMODES - k) & 63;

    float acc = 0.f;
#pragma unroll 4
    for (int i = 0; i < 32; ++i) {
        float xv  = xm[(size_t)(b * 32 + i) * NMODES + k];
        float xvf = xm[(size_t)(b * 32 + i) * NMODES + kf];
        float w   = w1[(size_t)(i * 32 + o) * NMODES + k];
        float wf  = w1[(size_t)(i * 32 + o) * NMODES + kf];
        acc = fmaf(xv, 0.5f * (w + wf), acc);
        acc = fmaf(xvf, 0.5f * (w - wf), acc);
    }
    const float sc = 1.0f / (float)N_LEN;
    z[(size_t)(b * 32 + o) * NMODES + k] = acc * sinf(pw[(size_t)o * NMODES + k]) * sc;
}

// ---------------------------------------------------------------------------
// GEMM2: out[row][n] = sum_k z[row][k] * Tt[k][n]   (1/N already in z)
// Block: 64 rows x 256 n, 256 threads, thread tile 8r x 8n
//   (ng = tid&31 -> n = n0+ng*8..+8 ; rg = tid>>5 -> rows rg*8..+8).
// z tile (64x64 = 16 KB) in LDS, broadcast reads (2 row-groups/wave = free).
// Tt streamed from global (4 KB/k-step working set -> L1). Per 4-k group:
// 8 LDS b128 + 8 L1 float4 per 256 FMA insts. Grid (16, 64).
// ---------------------------------------------------------------------------
#define G2_BR 64
#define G2_BN 256

__global__ __launch_bounds__(256) void gemm2(const float* __restrict__ Tt,
                                             const float* __restrict__ z,
                                             float* __restrict__ out) {
    __shared__ float zs[G2_BR * NMODES];    // 16 KB
    const int tid  = threadIdx.x;
    const int ng   = tid & 31;
    const int rg   = tid >> 5;
    const int row0 = blockIdx.x * G2_BR;
    const int nb   = blockIdx.y * G2_BN + ng * 8;

    // stage z[64][64] = 1024 float4, 4 per thread (coalesced)
#pragma unroll
    for (int it = 0; it < 4; ++it) {
        int idx = (it * 256 + tid) * 4;
        *(float4*)(zs + idx) = *(const float4*)(z + (size_t)row0 * NMODES + idx);
    }
    __syncthreads();

    float4 acc[8][2];
#pragma unroll
    for (int r = 0; r < 8; ++r) {
        acc[r][0] = make_float4(0.f, 0.f, 0.f, 0.f);
        acc[r][1] = make_float4(0.f, 0.f, 0.f, 0.f);
    }

    for (int k0 = 0; k0 < NMODES; k0 += 4) {
        float4 tv[4][2];
#pragma unroll
        for (int j = 0; j < 4; ++j) {
            const float* tp = Tt + (size_t)(k0 + j) * N_LEN + nb;
            tv[j][0] = *(const float4*)(tp);
            tv[j][1] = *(const float4*)(tp + 4);
        }
        float4 zv[8];
#pragma unroll
        for (int r = 0; r < 8; ++r)
            zv[r] = *(const float4*)(zs + (rg * 8 + r) * NMODES + k0);
#pragma unroll
        for (int r = 0; r < 8; ++r) {
            const float zc[4] = { zv[r].x, zv[r].y, zv[r].z, zv[r].w };
#pragma unroll
            for (int j = 0; j < 4; ++j) {
#pragma unroll
                for (int h = 0; h < 2; ++h) {
                    acc[r][h].x = fmaf(zc[j], tv[j][h].x, acc[r][h].x);
                    acc[r][h].y = fmaf(zc[j], tv[j][h].y, acc[r][h].y);
                    acc[r][h].z = fmaf(zc[j], tv[j][h].z, acc[r][h].z);
                    acc[r][h].w = fmaf(zc[j], tv[j][h].w, acc[r][h].w);
                }
            }
        }
    }

#pragma unroll
    for (int r = 0; r < 8; ++r) {
        float* p = out + (size_t)(row0 + rg * 8 + r) * N_LEN + nb;
        *(float4*)(p)     = acc[r][0];
        *(float4*)(p + 4) = acc[r][1];
    }
}

// ---------------------------------------------------------------------------
extern "C" void kernel_launch(void* const* d_in, const int* in_sizes, int n_in,
                              void* d_out, int out_size, void* d_ws, size_t ws_size,
                              hipStream_t stream) {
    const float* x  = (const float*)d_in[0];   // (32, 32, 16384)
    const float* w1 = (const float*)d_in[1];   // (32, 32, 64)
    const float* pw = (const float*)d_in[2];   // (32, 32, 64)
    float* out = (float*)d_out;                // (32, 32, 16384)
    float* ws  = (float*)d_ws;

    // Pick split-K factor by available workspace (constant across calls).
    int S = 128;
    while (S > 8) {
        size_t need = ((size_t)N_LEN * NMODES            // Tt
                     + (size_t)S * NROWS * NMODES        // partials
                     + 2u * NROWS * NMODES) * 4u;        // xm + z
        if (need <= ws_size) break;
        S >>= 1;
    }
    const int ntiles = N_LEN / S / G1_TN;

    float* Tt = ws;
    float* P  = ws + (size_t)N_LEN * NMODES;
    float* XM = P + (size_t)S * NROWS * NMODES;
    float* Z  = XM + (size_t)NROWS * NMODES;

    build_tt<<<dim3((N_LEN * NMODES) / 256), dim3(256), 0, stream>>>(Tt);

    gemm1<<<dim3(NROWS / G1_BR, S), dim3(256), 0, stream>>>(x, Tt, P, ntiles);

    reduce_xm<<<dim3(64), dim3(256), 0, stream>>>(P, XM, S);

    mixk<<<dim3(32, 8), dim3(256), 0, stream>>>(XM, w1, pw, Z);

    gemm2<<<dim3(NROWS / G2_BR, N_LEN / G2_BN), dim3(256), 0, stream>>>(Tt, Z, out);
}

// Round 5
// 145.925 us; speedup vs baseline: 1.7360x; 1.5436x over previous
//
#include <hip/hip_runtime.h>
#include <math.h>

// Problem constants
#define N_LEN 16384
#define NMODES 64
#define NROWS 1024          // B*C = 32*32
#define TWO_PI_OVER_N 3.8349519697141029e-04f
#define PAD 72              // LDS row pitch in bf16 elems (144 B, 16B-aligned)

typedef __bf16  bf16x8  __attribute__((ext_vector_type(8)));
typedef float   floatx16 __attribute__((ext_vector_type(16)));

// fp32 -> bf16 round-to-nearest-even (header-independent)
__device__ inline unsigned short f2b(float f) {
    unsigned u = __float_as_uint(f);
    u += 0x7fffu + ((u >> 16) & 1u);
    return (unsigned short)(u >> 16);
}

// ---------------------------------------------------------------------------
// Build bf16 cas tables: Ttb[m][n] (n contiguous, for gemm1 B-frags) and
// Ttn[n][m] (m contiguous, for gemm2 B-frags). Both coalesced writes.
// ---------------------------------------------------------------------------
__global__ __launch_bounds__(256) void build_tabs(unsigned short* __restrict__ Ttb,
                                                  unsigned short* __restrict__ Ttn) {
    int idx = blockIdx.x * 256 + threadIdx.x;   // 0 .. 2M-1
    int m, n;
    if (idx < N_LEN * NMODES) { m = idx >> 14; n = idx & (N_LEN - 1); }
    else { int j = idx - N_LEN * NMODES; n = j >> 6; m = j & 63; }
    float s, c;
    sincosf((float)((n * m) & (N_LEN - 1)) * TWO_PI_OVER_N, &s, &c);
    unsigned short v = f2b(c + s);
    if (idx < N_LEN * NMODES) Ttb[idx] = v;
    else                      Ttn[idx - N_LEN * NMODES] = v;
}

// ---------------------------------------------------------------------------
// GEMM1: part[s][row][mode] = sum_{n in chunk s} x[row][n] * Ttb[mode][n]
// MFMA 32x32x16 bf16. Block: 128 rows x 64 modes, 4 waves (wave w = rows
// w*32..+32, both 32-mode N-tiles). Chunk = ntiles*64 n; per 64-n sub-tile:
// stage x (fp32->bf16) + Ttb tile in LDS (reg double-buffered), 4 k-steps.
// A frag: xs[w*32+(lane&31)][ks*16+(lane>>5)*8]  (16B contiguous)
// B frag: ts[nt*32+(lane&31)][ks*16+(lane>>5)*8]
// D: col(mode)=lane&31, row=(r&3)+8*(r>>2)+4*(lane>>5)   [m74/m101]
// ---------------------------------------------------------------------------
#define G1_RB 128

__global__ __launch_bounds__(256) void gemm1(const float* __restrict__ x,
                                             const unsigned short* __restrict__ Ttb,
                                             float* __restrict__ part,
                                             int ntiles) {
    __shared__ unsigned short xs[G1_RB * PAD];   // 18.4 KB
    __shared__ unsigned short ts[64 * PAD];      //  9.2 KB
    const int tid  = threadIdx.x;
    const int lane = tid & 63;
    const int w    = tid >> 6;
    const int q    = lane >> 5;
    const int m    = lane & 31;
    const int row0 = blockIdx.x * G1_RB;
    const int n0   = blockIdx.y * (ntiles * 64);

    floatx16 acc0, acc1;
#pragma unroll
    for (int i = 0; i < 16; ++i) { acc0[i] = 0.f; acc1[i] = 0.f; }

    float4 xr[8];
    uint4  tr[2];
    // prologue: load sub-tile 0 into regs
    {
        const int base = n0;
#pragma unroll
        for (int it = 0; it < 8; ++it) {
            int cid = it * 256 + tid, rr = cid >> 4, cc = (cid & 15) * 4;
            xr[it] = *(const float4*)(x + (size_t)(row0 + rr) * N_LEN + base + cc);
        }
#pragma unroll
        for (int it = 0; it < 2; ++it) {
            int idx = it * 256 + tid, mm = idx >> 3, c = idx & 7;
            tr[it] = *(const uint4*)(Ttb + (size_t)mm * N_LEN + base + c * 8);
        }
    }

    for (int t = 0; t < ntiles; ++t) {
        __syncthreads();   // previous compute done before LDS overwrite
        // regs -> LDS (fp32 -> bf16 for x)
#pragma unroll
        for (int it = 0; it < 8; ++it) {
            int cid = it * 256 + tid, rr = cid >> 4, cc = (cid & 15) * 4;
            ushort4 v;
            v.x = f2b(xr[it].x); v.y = f2b(xr[it].y);
            v.z = f2b(xr[it].z); v.w = f2b(xr[it].w);
            *(ushort4*)(xs + rr * PAD + cc) = v;
        }
#pragma unroll
        for (int it = 0; it < 2; ++it) {
            int idx = it * 256 + tid, mm = idx >> 3, c = idx & 7;
            *(uint4*)(ts + mm * PAD + c * 8) = tr[it];
        }
        // prefetch next sub-tile (stays in flight during compute)
        if (t + 1 < ntiles) {
            const int base = n0 + (t + 1) * 64;
#pragma unroll
            for (int it = 0; it < 8; ++it) {
                int cid = it * 256 + tid, rr = cid >> 4, cc = (cid & 15) * 4;
                xr[it] = *(const float4*)(x + (size_t)(row0 + rr) * N_LEN + base + cc);
            }
#pragma unroll
            for (int it = 0; it < 2; ++it) {
                int idx = it * 256 + tid, mm = idx >> 3, c = idx & 7;
                tr[it] = *(const uint4*)(Ttb + (size_t)mm * N_LEN + base + c * 8);
            }
        }
        __syncthreads();
#pragma unroll
        for (int ks = 0; ks < 4; ++ks) {
            bf16x8 a  = *(const bf16x8*)(xs + (w * 32 + m) * PAD + ks * 16 + q * 8);
            bf16x8 b0 = *(const bf16x8*)(ts + (m)          * PAD + ks * 16 + q * 8);
            bf16x8 b1 = *(const bf16x8*)(ts + (32 + m)     * PAD + ks * 16 + q * 8);
            acc0 = __builtin_amdgcn_mfma_f32_32x32x16_bf16(a, b0, acc0, 0, 0, 0);
            acc1 = __builtin_amdgcn_mfma_f32_32x32x16_bf16(a, b1, acc1, 0, 0, 0);
        }
    }

    // store partials (fp32)
    float* pb = part + ((size_t)blockIdx.y * NROWS + row0 + w * 32) * NMODES;
#pragma unroll
    for (int r = 0; r < 16; ++r) {
        int rowt = (r & 3) + 8 * (r >> 2) + 4 * q;
        pb[rowt * NMODES + m]      = acc0[r];
        pb[rowt * NMODES + 32 + m] = acc1[r];
    }
}

// ---------------------------------------------------------------------------
// Reduce: xm[row][k] = sum_s part[s][row][k]
// ---------------------------------------------------------------------------
__global__ __launch_bounds__(256) void reduce_xm(const float* __restrict__ part,
                                                 float* __restrict__ xm, int S) {
    int gid = blockIdx.x * 256 + threadIdx.x;   // 16384 threads, float4 each
    float4 a = make_float4(0.f, 0.f, 0.f, 0.f);
#pragma unroll 4
    for (int s = 0; s < S; ++s) {
        float4 v = *(const float4*)(part + (size_t)s * (NROWS * NMODES) + (size_t)gid * 4);
        a.x += v.x; a.y += v.y; a.z += v.z; a.w += v.w;
    }
    *(float4*)(xm + (size_t)gid * 4) = a;
}

// ---------------------------------------------------------------------------
// Mix: z[b][o][k] = (1/N) * sin(pw[0][o][k]) *
//      sum_i xm[b][i][k]*ye + xm[b][i][kf]*yo,  kf=(64-k)&63.  Output bf16.
// ---------------------------------------------------------------------------
__global__ __launch_bounds__(256) void mixk(const float* __restrict__ xm,
                                            const float* __restrict__ w1,
                                            const float* __restrict__ pw,
                                            unsigned short* __restrict__ zb) {
    int k = threadIdx.x & 63;
    int wave = threadIdx.x >> 6;
    int b = blockIdx.x;
    int o = blockIdx.y * 4 + wave;
    int kf = (NMODES - k) & 63;

    float acc = 0.f;
#pragma unroll 4
    for (int i = 0; i < 32; ++i) {
        float xv  = xm[(size_t)(b * 32 + i) * NMODES + k];
        float xvf = xm[(size_t)(b * 32 + i) * NMODES + kf];
        float w   = w1[(size_t)(i * 32 + o) * NMODES + k];
        float wf  = w1[(size_t)(i * 32 + o) * NMODES + kf];
        acc = fmaf(xv, 0.5f * (w + wf), acc);
        acc = fmaf(xvf, 0.5f * (w - wf), acc);
    }
    const float sc = 1.0f / (float)N_LEN;
    zb[(size_t)(b * 32 + o) * NMODES + k] =
        f2b(acc * sinf(pw[(size_t)o * NMODES + k]) * sc);
}

// ---------------------------------------------------------------------------
// GEMM2: out[row][n] = sum_m z[row][m] * Ttn[n][m]   (1/N already in z)
// MFMA 32x32x16 bf16, K=64 = 4 k-steps. Block: 64 rows x 256 n, 4 waves
// (wave w: rows (w&1)*32..+32, n (w>>1)*128..+128 = 4 N-tiles).
// Stage z tile (64x64) + Ttn tile (256x64) once; store fp32 dwords
// (2 x 128B segments per store inst). Grid (16, 64).
// ---------------------------------------------------------------------------
#define G2_NB 256

__global__ __launch_bounds__(256) void gemm2(const unsigned short* __restrict__ Ttn,
                                             const unsigned short* __restrict__ zb,
                                             float* __restrict__ out) {
    __shared__ unsigned short tts[G2_NB * PAD];  // 36.9 KB
    __shared__ unsigned short zs[64 * PAD];      //  9.2 KB
    const int tid  = threadIdx.x;
    const int lane = tid & 63;
    const int w    = tid >> 6;
    const int q    = lane >> 5;
    const int m    = lane & 31;
    const int wr   = w & 1;
    const int wn   = w >> 1;
    const int row0 = blockIdx.x * 64;
    const int nb0  = blockIdx.y * G2_NB;

    // stage Ttn tile: 256 rows x 64 bf16 = 2048 16B-chunks, 8/thread
#pragma unroll
    for (int it = 0; it < 8; ++it) {
        int idx = it * 256 + tid, rr = idx >> 3, c = idx & 7;
        *(uint4*)(tts + rr * PAD + c * 8) =
            *(const uint4*)(Ttn + (size_t)(nb0 + rr) * NMODES + c * 8);
    }
    // stage z tile: 64 x 64 bf16 = 512 chunks, 2/thread
#pragma unroll
    for (int it = 0; it < 2; ++it) {
        int idx = it * 256 + tid, rr = idx >> 3, c = idx & 7;
        *(uint4*)(zs + rr * PAD + c * 8) =
            *(const uint4*)(zb + (size_t)(row0 + rr) * NMODES + c * 8);
    }
    __syncthreads();

    floatx16 acc[4];
#pragma unroll
    for (int nt = 0; nt < 4; ++nt)
#pragma unroll
        for (int i = 0; i < 16; ++i) acc[nt][i] = 0.f;

#pragma unroll
    for (int ks = 0; ks < 4; ++ks) {
        bf16x8 a = *(const bf16x8*)(zs + (wr * 32 + m) * PAD + ks * 16 + q * 8);
#pragma unroll
        for (int nt = 0; nt < 4; ++nt) {
            bf16x8 b = *(const bf16x8*)(tts + (wn * 128 + nt * 32 + m) * PAD + ks * 16 + q * 8);
            acc[nt] = __builtin_amdgcn_mfma_f32_32x32x16_bf16(a, b, acc[nt], 0, 0, 0);
        }
    }

#pragma unroll
    for (int nt = 0; nt < 4; ++nt) {
#pragma unroll
        for (int r = 0; r < 16; ++r) {
            int rowt = (r & 3) + 8 * (r >> 2) + 4 * q;
            out[(size_t)(row0 + wr * 32 + rowt) * N_LEN + nb0 + wn * 128 + nt * 32 + m]
                = acc[nt][r];
        }
    }
}

// ---------------------------------------------------------------------------
extern "C" void kernel_launch(void* const* d_in, const int* in_sizes, int n_in,
                              void* d_out, int out_size, void* d_ws, size_t ws_size,
                              hipStream_t stream) {
    const float* x  = (const float*)d_in[0];   // (32, 32, 16384)
    const float* w1 = (const float*)d_in[1];   // (32, 32, 64)
    const float* pw = (const float*)d_in[2];   // (32, 32, 64)
    float* out = (float*)d_out;                // (32, 32, 16384)

    // split-K factor by workspace (constant across calls)
    int S = 64;
    while (S > 8) {
        size_t need = 2u * (size_t)N_LEN * NMODES * 2u              // Ttb + Ttn
                    + (size_t)S * NROWS * NMODES * 4u               // partials
                    + (size_t)NROWS * NMODES * 4u                   // xm
                    + (size_t)NROWS * NMODES * 2u;                  // zb
        if (need <= ws_size) break;
        S >>= 1;
    }
    const int ntiles = N_LEN / S / 64;

    char* p = (char*)d_ws;
    unsigned short* Ttb = (unsigned short*)p;           p += (size_t)N_LEN * NMODES * 2;
    unsigned short* Ttn = (unsigned short*)p;           p += (size_t)N_LEN * NMODES * 2;
    float*          P   = (float*)p;                    p += (size_t)S * NROWS * NMODES * 4;
    float*          XM  = (float*)p;                    p += (size_t)NROWS * NMODES * 4;
    unsigned short* ZB  = (unsigned short*)p;

    build_tabs<<<dim3((2 * N_LEN * NMODES) / 256), dim3(256), 0, stream>>>(Ttb, Ttn);

    gemm1<<<dim3(NROWS / G1_RB, S), dim3(256), 0, stream>>>(x, Ttb, P, ntiles);

    reduce_xm<<<dim3(64), dim3(256), 0, stream>>>(P, XM, S);

    mixk<<<dim3(32, 8), dim3(256), 0, stream>>>(XM, w1, pw, ZB);

    gemm2<<<dim3(NROWS / 64, N_LEN / G2_NB), dim3(256), 0, stream>>>(Ttn, ZB, out);
}